// Round 1
// baseline (248.313 us; speedup 1.0000x reference)
//
#include <hip/hip_runtime.h>

// ---------------------------------------------------------------------------
// sxsGCN: h=[B=128,N=4096,3]; 3x { relu((adj@h)@W+b) }; then FC 12288->54->4096
// bf16 MFMA GEMMs adj[4096x4096] @ H[4096 x 512].
// R1..R8: see history. R8 = 64x64 tiles, k-sliced waves, 226us total
//   (fill 41us + 3 gemms ~43us each + prep/fc ~37us).
// R9: LDS-pipe + drain-stall attack:
//   - B operand PRE-PACKED in global in MFMA-frag order [k/32][c/16][lane][8]
//     (col=lane&15, k=(lane>>4)*8+j -- the layout the verified LDS frag reads
//     use). GEMM loads B direct global->VGPR, fully coalesced 16B/lane.
//     B never touches LDS. (R7 failed because it kept the UNPACKED layout.)
//   - 128x64 tiles, 256 blocks (1/CU), 512 thr = 2 M-halves x 4 k-slices;
//     A staged once per block, every LDS byte read once. LDS/step = 64KB
//     (~570cy) vs MFMA 620cy -> MFMA-dominant.
//   - raw s_barrier, ONE barrier per BK=128 step (stage(kt+1) is issued after
//     barrier(kt); reads of that buffer finished before barrier(kt)).
//     setprio(1) around the MFMA cluster (waves now role-split).
//   - XCD swizzle: each XCD owns 4 contiguous mi panels (4MB A -> L2-resident).
//   Producers write the packed layout: prep_k (G0), MODE0/1 epilogues (H1/H2g)
//   via the Ct transpose (16B/lane coalesced). H3 (fc1 input) unchanged.
// ---------------------------------------------------------------------------

typedef __bf16 bf16x8 __attribute__((ext_vector_type(8)));
typedef float  f32x4  __attribute__((ext_vector_type(4)));

#define N_NODE 4096
#define BATCH  128

__device__ __forceinline__ void async_copy16(const void* gsrc, void* ldst) {
    __builtin_amdgcn_global_load_lds(
        (const __attribute__((address_space(1))) void*)gsrc,
        (__attribute__((address_space(3))) void*)ldst,
        16, 0, 0);
}

// prep: [0,8192) cast adj->bf16 | [8192,9216) G0 packed = (X@W1) in B-frag
//       order | [9216,9243) zero hid
__global__ __launch_bounds__(256) void prep_k(const float* __restrict__ adj,
                                              __bf16* __restrict__ adjB,
                                              const float* __restrict__ X,
                                              const float* __restrict__ W1,
                                              __bf16* __restrict__ G0,
                                              float* __restrict__ hid_acc) {
    const int blk = blockIdx.x, tx = threadIdx.x;
    if (blk < 8192) {
        const size_t i = (size_t)blk * 256 + tx;       // group of 8
        const float4* a4 = (const float4*)adj;
        float4 u = a4[i * 2];
        float4 v = a4[i * 2 + 1];
        bf16x8 o = { (__bf16)u.x, (__bf16)u.y, (__bf16)u.z, (__bf16)u.w,
                     (__bf16)v.x, (__bf16)v.y, (__bf16)v.z, (__bf16)v.w };
        *(bf16x8*)(adjB + i * 8) = o;
    } else if (blk < 9216) {
        // one 16B packed chunk per thread: chunk g = (kc*32 + cb)*64 + lane'
        // holds 8 consecutive m (=k of stage-1 gemm) for one column c.
        const int g = (blk - 8192) * 256 + tx;
        const int lp = g & 63, cbg = (g >> 6) & 31, kc = g >> 11;
        const int c = cbg * 16 + (lp & 15);
        const int b = c >> 2, f = c & 3;
        const float w0 = W1[0 * 4 + f], w1 = W1[1 * 4 + f], w2 = W1[2 * 4 + f];
        const int mb = kc * 32 + ((lp >> 4) & 3) * 8;
        const float* Xb = X + (size_t)b * 12288 + (size_t)mb * 3;
        bf16x8 o;
#pragma unroll
        for (int j = 0; j < 8; ++j) {
            const float v = Xb[j * 3 + 0] * w0 + Xb[j * 3 + 1] * w1 + Xb[j * 3 + 2] * w2;
            o[j] = (__bf16)v;
        }
        *(bf16x8*)(G0 + (size_t)g * 8) = o;
    } else {
        const int i = (blk - 9216) * 256 + tx;
        if (i < BATCH * 54) hid_acc[i] = 0.f;
    }
}

// Fused GEMM + epilogue. Tile 128(M)x64(N), BK=128, 8 waves: wm=wave>>2 owns
// 64 rows, wk=wave&3 owns k-slice 32. A via swizzled global_load_lds (dbuf
// 2x32KB); B direct from packed global into regs (2 reg sets). Per step:
// vmcnt(0); s_barrier; 4x ds_read_b128; issue stage(kt+1); 16 MFMA.
// Epilogue: 2-step tree-reduce over wk (4x16KB slots, fits the 64KB LDS),
// wk==0 transposes into Ct[128][65], all 512 threads write:
//   MODE 0: relu(C+b1) -> packed bf16       MODE 1: (relu(C@W2+b2))@W3 packed
//   MODE 2: relu(C+b3), f<3 -> H3 fp32 [b*3+f][n]
template <int MODE>
__global__ __launch_bounds__(512, 2) void gcn_k(const __bf16* __restrict__ A,
                                                const __bf16* __restrict__ Bp,
                                                const float* __restrict__ Wa,
                                                const float* __restrict__ ba,
                                                const float* __restrict__ Wb,
                                                __bf16* __restrict__ Op,
                                                float* __restrict__ H3out) {
    __shared__ __align__(16) unsigned char smem[65536];
    const int tx = threadIdx.x;
    const int wave = tx >> 6, lane = tx & 63;
    const int quad = lane >> 4, lr = lane & 15;
    const int wm = wave >> 2, wk = wave & 3;

    const int l = blockIdx.x;
    const int xcd = l & 7, s = l >> 3;
    const int mi = xcd * 4 + (s & 3), ci = s >> 2;     // XCD gets 4 mi panels
    const int m0 = mi * 128, c0 = ci * 64;

    // A staging: 2048 16B chunks/buffer; thread tx issue q owns chunk
    // c = q*512+tx: row r=c>>4, pos p=c&15 holds logical k-chunk lk=(p-r)&15.
    const __bf16* gA[4];
#pragma unroll
    for (int q = 0; q < 4; ++q) {
        const int c = q * 512 + tx;
        const int r = c >> 4, p = c & 15;
        const int lk = (p - r) & 15;
        gA[q] = A + (size_t)(m0 + r) * 4096 + lk * 8;
    }
    // B packed frags: kc = kt*4 + wk, cb = ci*4 + j; 16B/lane coalesced.
    const __bf16* gB[4];
#pragma unroll
    for (int j = 0; j < 4; ++j)
        gB[j] = Bp + ((size_t)((wk * 32 + (ci * 4 + j)) * 64 + lane)) * 8;

    // A frag offsets (elements): row = wm*64+i*16+lr, k-chunk wk*4+quad.
    // (wm*64+i*16) == 0 mod 16 so stored pos = (wk*4+quad+lr)&15.
    const int posw = ((wk * 4 + quad + lr) & 15) * 8;
    int foffA[4];
#pragma unroll
    for (int i = 0; i < 4; ++i) foffA[i] = (wm * 64 + i * 16 + lr) * 128 + posw;

    f32x4 acc[4][4] = {};
    bf16x8 bv0[4], bv1[4];

    // prologue: stage kt=0
#pragma unroll
    for (int q = 0; q < 4; ++q)
        async_copy16(gA[q], smem + q * 8192 + tx * 16);
#pragma unroll
    for (int j = 0; j < 4; ++j) bv0[j] = *(const bf16x8*)(gB[j]);

#define GCN_ITER(KT, CUR, NXT)                                                 \
    {                                                                          \
        asm volatile("s_waitcnt vmcnt(0)" ::: "memory");                       \
        __builtin_amdgcn_s_barrier();                                          \
        const __bf16* Ab = (const __bf16*)(smem + ((KT) & 1) * 32768);         \
        bf16x8 af[4];                                                          \
        _Pragma("unroll") for (int i = 0; i < 4; ++i)                          \
            af[i] = *(const bf16x8*)(Ab + foffA[i]);                           \
        if ((KT) + 1 < 32) {                                                   \
            const int bo = (((KT) + 1) & 1) * 32768;                           \
            const int k0 = ((KT) + 1) * 128;                                   \
            _Pragma("unroll") for (int q = 0; q < 4; ++q)                      \
                async_copy16(gA[q] + k0, smem + bo + q * 8192 + tx * 16);      \
            _Pragma("unroll") for (int j = 0; j < 4; ++j)                      \
                NXT[j] = *(const bf16x8*)(gB[j] + ((KT) + 1) * 65536);         \
        }                                                                      \
        __builtin_amdgcn_s_setprio(1);                                         \
        _Pragma("unroll") for (int i = 0; i < 4; ++i)                          \
            _Pragma("unroll") for (int j = 0; j < 4; ++j)                      \
                acc[i][j] = __builtin_amdgcn_mfma_f32_16x16x32_bf16(           \
                    af[i], CUR[j], acc[i][j], 0, 0, 0);                        \
        __builtin_amdgcn_s_setprio(0);                                         \
    }

    for (int kt = 0; kt < 32; kt += 2) {
        GCN_ITER(kt, bv0, bv1)
        GCN_ITER(kt + 1, bv1, bv0)
    }
#undef GCN_ITER

    // ---- cross-wave k-reduce: 2-step tree (slots fit in 64KB) ----
    __syncthreads();
    float* part = (float*)smem;
    if (wk & 1) {                                  // wk 1,3 write
        float* slot = part + (wm * 2 + (wk >> 1)) * 4096;
#pragma unroll
        for (int t = 0; t < 16; ++t)
            *(f32x4*)(slot + lane * 64 + ((t + lane) & 15) * 4) = acc[t >> 2][t & 3];
    }
    __syncthreads();
    if (!(wk & 1)) {                               // wk 0,2 add partner
        const float* slot = part + (wm * 2 + (wk >> 1)) * 4096;
#pragma unroll
        for (int t = 0; t < 16; ++t)
            acc[t >> 2][t & 3] += *(const f32x4*)(slot + lane * 64 + ((t + lane) & 15) * 4);
    }
    __syncthreads();
    if (wk == 2) {                                 // wk 2 writes its sum
        float* slot = part + wm * 4096;
#pragma unroll
        for (int t = 0; t < 16; ++t)
            *(f32x4*)(slot + lane * 64 + ((t + lane) & 15) * 4) = acc[t >> 2][t & 3];
    }
    __syncthreads();
    if (wk == 0) {                                 // wk 0 holds full sum
#pragma unroll
        for (int t = 0; t < 16; ++t)
            acc[t >> 2][t & 3] += *(const f32x4*)(part + wm * 4096 + lane * 64 + ((t + lane) & 15) * 4);
    }
    __syncthreads();
    float* Ct = part;                              // [128][65]
    if (wk == 0) {
        // C/D: col=lane&15, row=quad*4+reg (harness-verified)
#pragma unroll
        for (int i = 0; i < 4; ++i)
#pragma unroll
            for (int j = 0; j < 4; ++j)
#pragma unroll
                for (int r = 0; r < 4; ++r)
                    Ct[(wm * 64 + i * 16 + quad * 4 + r) * 65 + j * 16 + lr] = acc[i][j][r];
    }
    __syncthreads();

    if (MODE == 0) {
#pragma unroll
        for (int it = 0; it < 2; ++it) {
            const int g = it * 512 + tx;           // 1024 packed chunks/block
            const int lp = g & 63, cbl = (g >> 6) & 3, kcl = g >> 8;
            const int cl = cbl * 16 + (lp & 15);
            const float bf = ba[cl & 3];
            const int mb = kcl * 32 + ((lp >> 4) & 3) * 8;
            bf16x8 o;
#pragma unroll
            for (int j = 0; j < 8; ++j)
                o[j] = (__bf16)fmaxf(Ct[(mb + j) * 65 + cl] + bf, 0.f);
            *(bf16x8*)(Op + ((size_t)((mi * 4 + kcl) * 32 + (ci * 4 + cbl)) * 64 + lp) * 8) = o;
        }
    } else if (MODE == 1) {
        float W2l[16], W3l[12], bl2[4];
#pragma unroll
        for (int i = 0; i < 16; ++i) W2l[i] = Wa[i];
#pragma unroll
        for (int i = 0; i < 12; ++i) W3l[i] = Wb[i];
#pragma unroll
        for (int i = 0; i < 4; ++i) bl2[i] = ba[i];
#pragma unroll
        for (int it = 0; it < 2; ++it) {
            const int g = it * 512 + tx;
            const int lp = g & 63, cbl = (g >> 6) & 3, kcl = g >> 8;
            const int cl = cbl * 16 + (lp & 15);
            const int bloc = cl >> 2, f3 = cl & 3;
            const int mb = kcl * 32 + ((lp >> 4) & 3) * 8;
            bf16x8 o;
#pragma unroll
            for (int j = 0; j < 8; ++j) {
                const float* row = &Ct[(mb + j) * 65 + bloc * 4];
                float v = 0.f;
                if (f3 < 3) {
#pragma unroll
                    for (int fo = 0; fo < 4; ++fo) {
                        const float tmp = fmaxf(row[0] * W2l[fo] + row[1] * W2l[4 + fo] +
                                                row[2] * W2l[8 + fo] + row[3] * W2l[12 + fo] +
                                                bl2[fo], 0.f);
                        // static indices only (avoid scratch): select W3 col
                        const float w3a = W3l[fo * 3 + 0], w3b = W3l[fo * 3 + 1],
                                    w3c = W3l[fo * 3 + 2];
                        v += tmp * (f3 == 0 ? w3a : (f3 == 1 ? w3b : w3c));
                    }
                }
                o[j] = (__bf16)v;                  // f3==3 -> 0 pad column
            }
            *(bf16x8*)(Op + ((size_t)((mi * 4 + kcl) * 32 + (ci * 4 + cbl)) * 64 + lp) * 8) = o;
        }
    } else {
        const int m_l = tx & 127, cq = tx >> 7;
#pragma unroll
        for (int t = 0; t < 16; ++t) {
            const int cl = cq * 16 + t;
            const int c = c0 + cl, b = c >> 2, f = c & 3;   // f == t&3
            if (f < 3)
                H3out[(size_t)(b * 3 + f) * N_NODE + m0 + m_l] =
                    fmaxf(Ct[m_l * 65 + cl] + ba[f], 0.f);
        }
    }
}

// fc1 split-K partial sums: grid (64 n-chunks, 8 b-groups of 16).
__global__ __launch_bounds__(256) void fc1p_k(const float* __restrict__ H3,
                                              const float* __restrict__ Wfc,
                                              float* __restrict__ hid_acc) {
    __shared__ float hs[16 * 192];       // [b][f][n]
    __shared__ float red[4][16][64];
    const int tx = threadIdx.x;
    const int wv = tx >> 6, lane = tx & 63;
    const int n0 = blockIdx.x * 64;
    const int b0 = blockIdx.y * 16;

    for (int idx = tx; idx < 3072; idx += 256) {
        const int n = idx & 63, f = (idx >> 6) % 3, b = idx / 192;
        hs[idx] = H3[((size_t)((b0 + b) * 3 + f)) * N_NODE + n0 + n];
    }
    __syncthreads();

    float acc[16];
#pragma unroll
    for (int b = 0; b < 16; ++b) acc[b] = 0.f;
    if (lane < 54) {
        const int nb = wv * 16;
        for (int n = 0; n < 16; ++n) {
#pragma unroll
            for (int f = 0; f < 3; ++f) {
                const float w = Wfc[((size_t)(n0 + nb + n) * 3 + f) * 54 + lane];
#pragma unroll
                for (int b = 0; b < 16; ++b)
                    acc[b] += hs[b * 192 + f * 64 + nb + n] * w;
            }
        }
    }
#pragma unroll
    for (int b = 0; b < 16; ++b) red[wv][b][lane] = acc[b];
    __syncthreads();
    if (wv == 0 && lane < 54) {
        for (int b = 0; b < 16; ++b) {
            const float s = red[0][b][lane] + red[1][b][lane] +
                            red[2][b][lane] + red[3][b][lane];
            atomicAdd(&hid_acc[(b0 + b) * 54 + lane], s);
        }
    }
}

// out[b][a] = sum_j relu(hid_acc[b][j]+bfc[j]) * Wout[j][a] + bout[a]
__global__ __launch_bounds__(256) void fc2_k(const float* __restrict__ hid_acc,
                                             const float* __restrict__ bfc,
                                             const float* __restrict__ Wout,
                                             const float* __restrict__ bout,
                                             float* __restrict__ out) {
    const int tx = threadIdx.x;
    const int a  = blockIdx.x * 256 + tx;
    const int b0 = blockIdx.y * 4;
    __shared__ float hs[4 * 54];
    if (tx < 216) {
        const int j = tx % 54;
        hs[tx] = fmaxf(hid_acc[b0 * 54 + tx] + bfc[j], 0.f);
    }
    __syncthreads();
    float a0 = 0.f, a1 = 0.f, a2 = 0.f, a3 = 0.f;
    for (int j = 0; j < 54; ++j) {
        float w = Wout[(size_t)j * N_NODE + a];
        a0 += hs[0 * 54 + j] * w;
        a1 += hs[1 * 54 + j] * w;
        a2 += hs[2 * 54 + j] * w;
        a3 += hs[3 * 54 + j] * w;
    }
    float bo = bout[a];
    out[(size_t)(b0 + 0) * N_NODE + a] = a0 + bo;
    out[(size_t)(b0 + 1) * N_NODE + a] = a1 + bo;
    out[(size_t)(b0 + 2) * N_NODE + a] = a2 + bo;
    out[(size_t)(b0 + 3) * N_NODE + a] = a3 + bo;
}

extern "C" void kernel_launch(void* const* d_in, const int* in_sizes, int n_in,
                              void* d_out, int out_size, void* d_ws, size_t ws_size,
                              hipStream_t stream) {
    const float* X    = (const float*)d_in[0];
    const float* adj  = (const float*)d_in[1];
    const float* W1   = (const float*)d_in[2];
    const float* b1   = (const float*)d_in[3];
    const float* W2   = (const float*)d_in[4];
    const float* b2   = (const float*)d_in[5];
    const float* W3   = (const float*)d_in[6];
    const float* b3   = (const float*)d_in[7];
    const float* Wfc  = (const float*)d_in[8];
    const float* bfc  = (const float*)d_in[9];
    const float* Wout = (const float*)d_in[10];
    const float* bout = (const float*)d_in[11];
    float* out = (float*)d_out;

    // ws: adjB 32MB | G0 packed 4MB | H1 packed 4MB | H2g packed 4MB
    //   | H3 fp32 [384][4096] 6MB | hid [128][54]
    char* w = (char*)d_ws;
    __bf16* adjB = (__bf16*)w;
    __bf16* G0   = (__bf16*)(w + 33554432);
    __bf16* H1   = (__bf16*)(w + 33554432 + 4194304);
    __bf16* H2g  = (__bf16*)(w + 33554432 + 2 * 4194304);
    float*  H3   = (float*)(w + 33554432 + 3 * 4194304);
    float*  hid  = (float*)(w + 33554432 + 3 * 4194304 + 6291456);

    prep_k<<<9243, 256, 0, stream>>>(adj, adjB, X, W1, G0, hid);

    // stage 1: H1 = relu(adj @ G0 + b1)            (W1 pre-applied in prep)
    gcn_k<0><<<256, 512, 0, stream>>>(adjB, G0, nullptr, b1, nullptr, H1, nullptr);
    // stage 2: H2g = (relu(adj @ H1 @ W2 + b2)) @ W3, padded f=4
    gcn_k<1><<<256, 512, 0, stream>>>(adjB, H1, W2, b2, W3, H2g, nullptr);
    // stage 3: H3 = relu(adj @ H2g + b3), f<3, fp32
    gcn_k<2><<<256, 512, 0, stream>>>(adjB, H2g, nullptr, b3, nullptr, nullptr, H3);

    // FC head
    fc1p_k<<<dim3(64, 8), 256, 0, stream>>>(H3, Wfc, hid);
    fc2_k<<<dim3(16, 32), 256, 0, stream>>>(hid, bfc, Wout, bout, out);
}

// Round 2
// 231.993 us; speedup vs baseline: 1.0703x; 1.0703x over previous
//
#include <hip/hip_runtime.h>

// ---------------------------------------------------------------------------
// sxsGCN: h=[B=128,N=4096,3]; 3x { relu((adj@h)@W+b) }; then FC 12288->54->4096
// bf16 MFMA GEMMs adj[4096x4096] @ H[4096 x 512].
// R1..R8: see history. R9: packed-B direct-to-reg + 128x64 tiles, 1 blk/CU:
//   neutral (41us/gemm). FETCH=32.8MB proves B L2-resident, A read once; but
//   MfmaUtil 15%, HBM 11% -> latency-serialized: 1-deep prefetch + vmcnt(0)
//   drain = ~3100 cy/step (L2 round trip exposed every step, nothing else
//   resident to overlap).
// R10: depth-3 pipeline (T3/T4):
//   - 4 LDS buffers (4x32KB=128KB; 1 blk/CU anyway) + 4 static B-reg sets,
//     K-loop unrolled x4 so all buffer indices are compile-time.
//   - counted s_waitcnt vmcnt(16) before each barrier: 24 VMEM insts in
//     flight (3 tile batches x 8), retire only the oldest batch. Tail steps
//     16/16/8/0. lgkmcnt(0) before each barrier => buffer overwrite is
//     race-free (all waves' ds_reads of that buffer retired before barrier).
//   - asm ""::"memory" fences keep tile batches in issue order so the vmcnt
//     count is exact (B loads are plain loads; must not migrate batches).
//   - cross-wave k-reduce exchange rewritten t-major LINEAR (lane-contiguous
//     16B) -> kills the 8-way bank conflicts (1.28M -> ~0).
// ---------------------------------------------------------------------------

typedef __bf16 bf16x8 __attribute__((ext_vector_type(8)));
typedef float  f32x4  __attribute__((ext_vector_type(4)));

#define N_NODE 4096
#define BATCH  128

__device__ __forceinline__ void async_copy16(const void* gsrc, void* ldst) {
    __builtin_amdgcn_global_load_lds(
        (const __attribute__((address_space(1))) void*)gsrc,
        (__attribute__((address_space(3))) void*)ldst,
        16, 0, 0);
}

// prep: [0,8192) cast adj->bf16 | [8192,9216) G0 packed = (X@W1) in B-frag
//       order | [9216,9243) zero hid
__global__ __launch_bounds__(256) void prep_k(const float* __restrict__ adj,
                                              __bf16* __restrict__ adjB,
                                              const float* __restrict__ X,
                                              const float* __restrict__ W1,
                                              __bf16* __restrict__ G0,
                                              float* __restrict__ hid_acc) {
    const int blk = blockIdx.x, tx = threadIdx.x;
    if (blk < 8192) {
        const size_t i = (size_t)blk * 256 + tx;       // group of 8
        const float4* a4 = (const float4*)adj;
        float4 u = a4[i * 2];
        float4 v = a4[i * 2 + 1];
        bf16x8 o = { (__bf16)u.x, (__bf16)u.y, (__bf16)u.z, (__bf16)u.w,
                     (__bf16)v.x, (__bf16)v.y, (__bf16)v.z, (__bf16)v.w };
        *(bf16x8*)(adjB + i * 8) = o;
    } else if (blk < 9216) {
        // one 16B packed chunk per thread: chunk g = (kc*32 + cb)*64 + lane'
        const int g = (blk - 8192) * 256 + tx;
        const int lp = g & 63, cbg = (g >> 6) & 31, kc = g >> 11;
        const int c = cbg * 16 + (lp & 15);
        const int b = c >> 2, f = c & 3;
        const float w0 = W1[0 * 4 + f], w1 = W1[1 * 4 + f], w2 = W1[2 * 4 + f];
        const int mb = kc * 32 + ((lp >> 4) & 3) * 8;
        const float* Xb = X + (size_t)b * 12288 + (size_t)mb * 3;
        bf16x8 o;
#pragma unroll
        for (int j = 0; j < 8; ++j) {
            const float v = Xb[j * 3 + 0] * w0 + Xb[j * 3 + 1] * w1 + Xb[j * 3 + 2] * w2;
            o[j] = (__bf16)v;
        }
        *(bf16x8*)(G0 + (size_t)g * 8) = o;
    } else {
        const int i = (blk - 9216) * 256 + tx;
        if (i < BATCH * 54) hid_acc[i] = 0.f;
    }
}

// Fused GEMM + epilogue. Tile 128(M)x64(N), BK=128, 8 waves: wm=wave>>2 owns
// 64 rows, wk=wave&3 owns k-slice 32. A via swizzled global_load_lds, 4-deep
// buffer ring (128KB); B direct from packed global into 4 static reg sets.
// Per step: vmcnt(16)+lgkmcnt(0); s_barrier; 4x ds_read_b128; issue stage
// (kt+3); 16 MFMA. Epilogue: linear 2-step tree-reduce over wk, wk==0
// transposes into Ct[128][65] @ +64KB, all 512 threads write MODE output.
template <int MODE>
__global__ __launch_bounds__(512, 2) void gcn_k(const __bf16* __restrict__ A,
                                                const __bf16* __restrict__ Bp,
                                                const float* __restrict__ Wa,
                                                const float* __restrict__ ba,
                                                const float* __restrict__ Wb,
                                                __bf16* __restrict__ Op,
                                                float* __restrict__ H3out) {
    __shared__ __align__(16) unsigned char smem[131072];
    const int tx = threadIdx.x;
    const int wave = tx >> 6, lane = tx & 63;
    const int quad = lane >> 4, lr = lane & 15;
    const int wm = wave >> 2, wk = wave & 3;

    const int l = blockIdx.x;
    const int xcd = l & 7, s = l >> 3;
    const int mi = xcd * 4 + (s & 3), ci = s >> 2;     // XCD gets 4 mi panels
    const int m0 = mi * 128, c0 = ci * 64;

    // A staging: 2048 16B chunks/buffer; thread tx issue q owns chunk
    // c = q*512+tx: row r=c>>4, pos p=c&15 holds logical k-chunk lk=(p-r)&15.
    const __bf16* gA[4];
#pragma unroll
    for (int q = 0; q < 4; ++q) {
        const int c = q * 512 + tx;
        const int r = c >> 4, p = c & 15;
        const int lk = (p - r) & 15;
        gA[q] = A + (size_t)(m0 + r) * 4096 + lk * 8;
    }
    // B packed frags: kc = kt*4 + wk, cb = ci*4 + j; 16B/lane coalesced.
    const __bf16* gB[4];
#pragma unroll
    for (int j = 0; j < 4; ++j)
        gB[j] = Bp + ((size_t)((wk * 32 + (ci * 4 + j)) * 64 + lane)) * 8;

    // A frag offsets (elements): row = wm*64+i*16+lr, k-chunk wk*4+quad.
    const int posw = ((wk * 4 + quad + lr) & 15) * 8;
    int foffA[4];
#pragma unroll
    for (int i = 0; i < 4; ++i) foffA[i] = (wm * 64 + i * 16 + lr) * 128 + posw;

    f32x4 acc[4][4] = {};
    bf16x8 bv0[4], bv1[4], bv2[4], bv3[4];

    // prologue: stage tiles 0,1,2 into bufs 0,1,2 (batch order = vmcnt order)
#pragma unroll
    for (int q = 0; q < 4; ++q) async_copy16(gA[q], smem + q * 8192 + tx * 16);
#pragma unroll
    for (int j = 0; j < 4; ++j) bv0[j] = *(const bf16x8*)(gB[j]);
    asm volatile("" ::: "memory");
#pragma unroll
    for (int q = 0; q < 4; ++q) async_copy16(gA[q] + 128, smem + 32768 + q * 8192 + tx * 16);
#pragma unroll
    for (int j = 0; j < 4; ++j) bv1[j] = *(const bf16x8*)(gB[j] + 65536);
    asm volatile("" ::: "memory");
#pragma unroll
    for (int q = 0; q < 4; ++q) async_copy16(gA[q] + 256, smem + 65536 + q * 8192 + tx * 16);
#pragma unroll
    for (int j = 0; j < 4; ++j) bv2[j] = *(const bf16x8*)(gB[j] + 131072);
    asm volatile("" ::: "memory");

#define GCN_STEP(KT, P, WAIT, PF, CUR, NXT)                                    \
    {                                                                          \
        asm volatile(WAIT ::: "memory");                                       \
        __builtin_amdgcn_s_barrier();                                          \
        const __bf16* Ab = (const __bf16*)(smem + (P) * 32768);                \
        bf16x8 af[4];                                                          \
        _Pragma("unroll") for (int i = 0; i < 4; ++i)                          \
            af[i] = *(const bf16x8*)(Ab + foffA[i]);                           \
        if (PF) {                                                              \
            const int nt_ = (KT) + 3;                                          \
            unsigned char* bo_ = smem + (((P) + 3) & 3) * 32768;               \
            _Pragma("unroll") for (int q = 0; q < 4; ++q)                      \
                async_copy16(gA[q] + nt_ * 128, bo_ + q * 8192 + tx * 16);     \
            _Pragma("unroll") for (int j = 0; j < 4; ++j)                      \
                NXT[j] = *(const bf16x8*)(gB[j] + (size_t)nt_ * 65536);        \
        }                                                                      \
        __builtin_amdgcn_s_setprio(1);                                         \
        _Pragma("unroll") for (int i = 0; i < 4; ++i)                          \
            _Pragma("unroll") for (int j = 0; j < 4; ++j)                      \
                acc[i][j] = __builtin_amdgcn_mfma_f32_16x16x32_bf16(           \
                    af[i], CUR[j], acc[i][j], 0, 0, 0);                        \
        __builtin_amdgcn_s_setprio(0);                                         \
    }

    for (int kt = 0; kt < 28; kt += 4) {
        GCN_STEP(kt + 0, 0, "s_waitcnt vmcnt(16) lgkmcnt(0)", 1, bv0, bv3)
        GCN_STEP(kt + 1, 1, "s_waitcnt vmcnt(16) lgkmcnt(0)", 1, bv1, bv0)
        GCN_STEP(kt + 2, 2, "s_waitcnt vmcnt(16) lgkmcnt(0)", 1, bv2, bv1)
        GCN_STEP(kt + 3, 3, "s_waitcnt vmcnt(16) lgkmcnt(0)", 1, bv3, bv2)
    }
    GCN_STEP(28, 0, "s_waitcnt vmcnt(16) lgkmcnt(0)", 1, bv0, bv3)
    GCN_STEP(29, 1, "s_waitcnt vmcnt(16) lgkmcnt(0)", 0, bv1, bv0)
    GCN_STEP(30, 2, "s_waitcnt vmcnt(8) lgkmcnt(0)",  0, bv2, bv1)
    GCN_STEP(31, 3, "s_waitcnt vmcnt(0) lgkmcnt(0)",  0, bv3, bv2)
#undef GCN_STEP

    // ---- cross-wave k-reduce: linear t-major exchange (conflict-free) ----
    __syncthreads();
    float* part = (float*)smem;                        // 4 slots x 16KB
    const int sb = (wm * 2 + (wk >> 1)) * 4096;
    if (wk & 1) {                                      // wk 1,3 write
#pragma unroll
        for (int t = 0; t < 16; ++t)
            *(f32x4*)(part + sb + t * 256 + lane * 4) = acc[t >> 2][t & 3];
    }
    __syncthreads();
    if (!(wk & 1)) {                                   // wk 0,2 add partner
#pragma unroll
        for (int t = 0; t < 16; ++t)
            acc[t >> 2][t & 3] += *(const f32x4*)(part + sb + t * 256 + lane * 4);
    }
    __syncthreads();
    if (wk == 2) {                                     // wk 2 writes its sum
#pragma unroll
        for (int t = 0; t < 16; ++t)
            *(f32x4*)(part + wm * 4096 + t * 256 + lane * 4) = acc[t >> 2][t & 3];
    }
    __syncthreads();
    if (wk == 0) {                                     // wk 0 holds full sum
#pragma unroll
        for (int t = 0; t < 16; ++t)
            acc[t >> 2][t & 3] += *(const f32x4*)(part + wm * 4096 + t * 256 + lane * 4);
    }
    __syncthreads();
    float* Ct = (float*)(smem + 65536);                // [128][65]
    if (wk == 0) {
        // C/D: col=lane&15, row=quad*4+reg (harness-verified)
#pragma unroll
        for (int i = 0; i < 4; ++i)
#pragma unroll
            for (int j = 0; j < 4; ++j)
#pragma unroll
                for (int r = 0; r < 4; ++r)
                    Ct[(wm * 64 + i * 16 + quad * 4 + r) * 65 + j * 16 + lr] = acc[i][j][r];
    }
    __syncthreads();

    if (MODE == 0) {
#pragma unroll
        for (int it = 0; it < 2; ++it) {
            const int g = it * 512 + tx;           // 1024 packed chunks/block
            const int lp = g & 63, cbl = (g >> 6) & 3, kcl = g >> 8;
            const int cl = cbl * 16 + (lp & 15);
            const float bf = ba[cl & 3];
            const int mb = kcl * 32 + ((lp >> 4) & 3) * 8;
            bf16x8 o;
#pragma unroll
            for (int j = 0; j < 8; ++j)
                o[j] = (__bf16)fmaxf(Ct[(mb + j) * 65 + cl] + bf, 0.f);
            *(bf16x8*)(Op + ((size_t)((mi * 4 + kcl) * 32 + (ci * 4 + cbl)) * 64 + lp) * 8) = o;
        }
    } else if (MODE == 1) {
        float W2l[16], W3l[12], bl2[4];
#pragma unroll
        for (int i = 0; i < 16; ++i) W2l[i] = Wa[i];
#pragma unroll
        for (int i = 0; i < 12; ++i) W3l[i] = Wb[i];
#pragma unroll
        for (int i = 0; i < 4; ++i) bl2[i] = ba[i];
#pragma unroll
        for (int it = 0; it < 2; ++it) {
            const int g = it * 512 + tx;
            const int lp = g & 63, cbl = (g >> 6) & 3, kcl = g >> 8;
            const int cl = cbl * 16 + (lp & 15);
            const int bloc = cl >> 2, f3 = cl & 3;
            const int mb = kcl * 32 + ((lp >> 4) & 3) * 8;
            bf16x8 o;
#pragma unroll
            for (int j = 0; j < 8; ++j) {
                const float* row = &Ct[(mb + j) * 65 + bloc * 4];
                float v = 0.f;
                if (f3 < 3) {
#pragma unroll
                    for (int fo = 0; fo < 4; ++fo) {
                        const float tmp = fmaxf(row[0] * W2l[fo] + row[1] * W2l[4 + fo] +
                                                row[2] * W2l[8 + fo] + row[3] * W2l[12 + fo] +
                                                bl2[fo], 0.f);
                        const float w3a = W3l[fo * 3 + 0], w3b = W3l[fo * 3 + 1],
                                    w3c = W3l[fo * 3 + 2];
                        v += tmp * (f3 == 0 ? w3a : (f3 == 1 ? w3b : w3c));
                    }
                }
                o[j] = (__bf16)v;                  // f3==3 -> 0 pad column
            }
            *(bf16x8*)(Op + ((size_t)((mi * 4 + kcl) * 32 + (ci * 4 + cbl)) * 64 + lp) * 8) = o;
        }
    } else {
        const int m_l = tx & 127, cq = tx >> 7;
#pragma unroll
        for (int t = 0; t < 16; ++t) {
            const int cl = cq * 16 + t;
            const int c = c0 + cl, b = c >> 2, f = c & 3;   // f == t&3
            if (f < 3)
                H3out[(size_t)(b * 3 + f) * N_NODE + m0 + m_l] =
                    fmaxf(Ct[m_l * 65 + cl] + ba[f], 0.f);
        }
    }
}

// fc1 split-K partial sums: grid (64 n-chunks, 8 b-groups of 16).
__global__ __launch_bounds__(256) void fc1p_k(const float* __restrict__ H3,
                                              const float* __restrict__ Wfc,
                                              float* __restrict__ hid_acc) {
    __shared__ float hs[16 * 192];       // [b][f][n]
    __shared__ float red[4][16][64];
    const int tx = threadIdx.x;
    const int wv = tx >> 6, lane = tx & 63;
    const int n0 = blockIdx.x * 64;
    const int b0 = blockIdx.y * 16;

    for (int idx = tx; idx < 3072; idx += 256) {
        const int n = idx & 63, f = (idx >> 6) % 3, b = idx / 192;
        hs[idx] = H3[((size_t)((b0 + b) * 3 + f)) * N_NODE + n0 + n];
    }
    __syncthreads();

    float acc[16];
#pragma unroll
    for (int b = 0; b < 16; ++b) acc[b] = 0.f;
    if (lane < 54) {
        const int nb = wv * 16;
        for (int n = 0; n < 16; ++n) {
#pragma unroll
            for (int f = 0; f < 3; ++f) {
                const float w = Wfc[((size_t)(n0 + nb + n) * 3 + f) * 54 + lane];
#pragma unroll
                for (int b = 0; b < 16; ++b)
                    acc[b] += hs[b * 192 + f * 64 + nb + n] * w;
            }
        }
    }
#pragma unroll
    for (int b = 0; b < 16; ++b) red[wv][b][lane] = acc[b];
    __syncthreads();
    if (wv == 0 && lane < 54) {
        for (int b = 0; b < 16; ++b) {
            const float s = red[0][b][lane] + red[1][b][lane] +
                            red[2][b][lane] + red[3][b][lane];
            atomicAdd(&hid_acc[(b0 + b) * 54 + lane], s);
        }
    }
}

// out[b][a] = sum_j relu(hid_acc[b][j]+bfc[j]) * Wout[j][a] + bout[a]
__global__ __launch_bounds__(256) void fc2_k(const float* __restrict__ hid_acc,
                                             const float* __restrict__ bfc,
                                             const float* __restrict__ Wout,
                                             const float* __restrict__ bout,
                                             float* __restrict__ out) {
    const int tx = threadIdx.x;
    const int a  = blockIdx.x * 256 + tx;
    const int b0 = blockIdx.y * 4;
    __shared__ float hs[4 * 54];
    if (tx < 216) {
        const int j = tx % 54;
        hs[tx] = fmaxf(hid_acc[b0 * 54 + tx] + bfc[j], 0.f);
    }
    __syncthreads();
    float a0 = 0.f, a1 = 0.f, a2 = 0.f, a3 = 0.f;
    for (int j = 0; j < 54; ++j) {
        float w = Wout[(size_t)j * N_NODE + a];
        a0 += hs[0 * 54 + j] * w;
        a1 += hs[1 * 54 + j] * w;
        a2 += hs[2 * 54 + j] * w;
        a3 += hs[3 * 54 + j] * w;
    }
    float bo = bout[a];
    out[(size_t)(b0 + 0) * N_NODE + a] = a0 + bo;
    out[(size_t)(b0 + 1) * N_NODE + a] = a1 + bo;
    out[(size_t)(b0 + 2) * N_NODE + a] = a2 + bo;
    out[(size_t)(b0 + 3) * N_NODE + a] = a3 + bo;
}

extern "C" void kernel_launch(void* const* d_in, const int* in_sizes, int n_in,
                              void* d_out, int out_size, void* d_ws, size_t ws_size,
                              hipStream_t stream) {
    const float* X    = (const float*)d_in[0];
    const float* adj  = (const float*)d_in[1];
    const float* W1   = (const float*)d_in[2];
    const float* b1   = (const float*)d_in[3];
    const float* W2   = (const float*)d_in[4];
    const float* b2   = (const float*)d_in[5];
    const float* W3   = (const float*)d_in[6];
    const float* b3   = (const float*)d_in[7];
    const float* Wfc  = (const float*)d_in[8];
    const float* bfc  = (const float*)d_in[9];
    const float* Wout = (const float*)d_in[10];
    const float* bout = (const float*)d_in[11];
    float* out = (float*)d_out;

    // ws: adjB 32MB | G0 packed 4MB | H1 packed 4MB | H2g packed 4MB
    //   | H3 fp32 [384][4096] 6MB | hid [128][54]
    char* w = (char*)d_ws;
    __bf16* adjB = (__bf16*)w;
    __bf16* G0   = (__bf16*)(w + 33554432);
    __bf16* H1   = (__bf16*)(w + 33554432 + 4194304);
    __bf16* H2g  = (__bf16*)(w + 33554432 + 2 * 4194304);
    float*  H3   = (float*)(w + 33554432 + 3 * 4194304);
    float*  hid  = (float*)(w + 33554432 + 3 * 4194304 + 6291456);

    prep_k<<<9243, 256, 0, stream>>>(adj, adjB, X, W1, G0, hid);

    // stage 1: H1 = relu(adj @ G0 + b1)            (W1 pre-applied in prep)
    gcn_k<0><<<256, 512, 0, stream>>>(adjB, G0, nullptr, b1, nullptr, H1, nullptr);
    // stage 2: H2g = (relu(adj @ H1 @ W2 + b2)) @ W3, padded f=4
    gcn_k<1><<<256, 512, 0, stream>>>(adjB, H1, W2, b2, W3, H2g, nullptr);
    // stage 3: H3 = relu(adj @ H2g + b3), f<3, fp32
    gcn_k<2><<<256, 512, 0, stream>>>(adjB, H2g, nullptr, b3, nullptr, nullptr, H3);

    // FC head
    fc1p_k<<<dim3(64, 8), 256, 0, stream>>>(H3, Wfc, hid);
    fc2_k<<<dim3(16, 32), 256, 0, stream>>>(hid, bfc, Wout, bout, out);
}

// Round 3
// 225.191 us; speedup vs baseline: 1.1027x; 1.0302x over previous
//
#include <hip/hip_runtime.h>

// ---------------------------------------------------------------------------
// sxsGCN: h=[B=128,N=4096,3]; 3x { relu((adj@h)@W+b) }; then FC 12288->54->4096
// bf16 MFMA GEMMs adj[4096x4096] @ H[4096 x 512].
// R9: packed-B direct-to-reg + 128x64, 1 blk/CU: latency-serialized, 41us.
// R10: depth-3 counted vmcnt(16) pipeline, 4-buf ring: ~36us/gemm. Still
//   1 blk/CU 8-wave lockstep: per-step time = max over waves, no other
//   block resident to absorb jitter (all pipes <20% busy).
// R11: 64x64 tiles, 512 blocks, 256 thr (4 waves, k-slice 32 each),
//   4x16KB buffer ring = 64KB LDS -> 2 blocks/CU. Keeps packed-B
//   direct-to-reg + depth-3 counted vmcnt + linear reduce exchange.
//   Per-CU L2 traffic/step unchanged; inter-block TLP hides barrier stalls.
//   Ct stride 65->66 (65 was 4-way bank conflict on transpose scatter).
// ---------------------------------------------------------------------------

typedef __bf16 bf16x8 __attribute__((ext_vector_type(8)));
typedef float  f32x4  __attribute__((ext_vector_type(4)));

#define N_NODE 4096
#define BATCH  128

__device__ __forceinline__ void async_copy16(const void* gsrc, void* ldst) {
    __builtin_amdgcn_global_load_lds(
        (const __attribute__((address_space(1))) void*)gsrc,
        (__attribute__((address_space(3))) void*)ldst,
        16, 0, 0);
}

// prep: [0,8192) cast adj->bf16 | [8192,9216) G0 packed = (X@W1) in B-frag
//       order | [9216,9243) zero hid
__global__ __launch_bounds__(256) void prep_k(const float* __restrict__ adj,
                                              __bf16* __restrict__ adjB,
                                              const float* __restrict__ X,
                                              const float* __restrict__ W1,
                                              __bf16* __restrict__ G0,
                                              float* __restrict__ hid_acc) {
    const int blk = blockIdx.x, tx = threadIdx.x;
    if (blk < 8192) {
        const size_t i = (size_t)blk * 256 + tx;       // group of 8
        const float4* a4 = (const float4*)adj;
        float4 u = a4[i * 2];
        float4 v = a4[i * 2 + 1];
        bf16x8 o = { (__bf16)u.x, (__bf16)u.y, (__bf16)u.z, (__bf16)u.w,
                     (__bf16)v.x, (__bf16)v.y, (__bf16)v.z, (__bf16)v.w };
        *(bf16x8*)(adjB + i * 8) = o;
    } else if (blk < 9216) {
        // one 16B packed chunk per thread: chunk g = (kc*32 + cb)*64 + lane'
        const int g = (blk - 8192) * 256 + tx;
        const int lp = g & 63, cbg = (g >> 6) & 31, kc = g >> 11;
        const int c = cbg * 16 + (lp & 15);
        const int b = c >> 2, f = c & 3;
        const float w0 = W1[0 * 4 + f], w1 = W1[1 * 4 + f], w2 = W1[2 * 4 + f];
        const int mb = kc * 32 + ((lp >> 4) & 3) * 8;
        const float* Xb = X + (size_t)b * 12288 + (size_t)mb * 3;
        bf16x8 o;
#pragma unroll
        for (int j = 0; j < 8; ++j) {
            const float v = Xb[j * 3 + 0] * w0 + Xb[j * 3 + 1] * w1 + Xb[j * 3 + 2] * w2;
            o[j] = (__bf16)v;
        }
        *(bf16x8*)(G0 + (size_t)g * 8) = o;
    } else {
        const int i = (blk - 9216) * 256 + tx;
        if (i < BATCH * 54) hid_acc[i] = 0.f;
    }
}

// Fused GEMM + epilogue. Tile 64(M)x64(N), BK=128, 4 waves: wk=wave owns
// k-slice [wk*32, wk*32+32) and computes the FULL 64x64 over it (4x4 frags).
// A via swizzled global_load_lds, 4-deep 16KB buffer ring; B direct from
// packed global into 4 static reg sets. Per step: vmcnt(16)+lgkmcnt(0);
// s_barrier; 4x ds_read_b128; issue stage(kt+3); 16 MFMA.
// Epilogue: linear tree-reduce over wk, wave0 transposes into Ct[64][66],
// all 256 threads write MODE output:
//   MODE 0: relu(C+b1) -> packed bf16       MODE 1: (relu(C@W2+b2))@W3 packed
//   MODE 2: relu(C+b3), f<3 -> H3 fp32 [b*3+f][n]
template <int MODE>
__global__ __launch_bounds__(256, 2) void gcn_k(const __bf16* __restrict__ A,
                                                const __bf16* __restrict__ Bp,
                                                const float* __restrict__ Wa,
                                                const float* __restrict__ ba,
                                                const float* __restrict__ Wb,
                                                __bf16* __restrict__ Op,
                                                float* __restrict__ H3out) {
    __shared__ __align__(16) unsigned char smem[65536];
    const int tx = threadIdx.x;
    const int wk = tx >> 6, lane = tx & 63;
    const int quad = lane >> 4, lr = lane & 15;

    const int l = blockIdx.x;
    const int xcd = l & 7, s = l >> 3;
    const int mi = xcd * 8 + (s & 7), ci = s >> 3;     // XCD: 8 mi panels
    const int m0 = mi * 64, c0 = ci * 64;

    // A staging: 1024 16B chunks/buffer; thread tx issue q owns chunk
    // c = q*256+tx: row r=c>>4, pos p=c&15 holds logical k-chunk lk=(p-r)&15.
    const __bf16* gA[4];
#pragma unroll
    for (int q = 0; q < 4; ++q) {
        const int c = q * 256 + tx;
        const int r = c >> 4, p = c & 15;
        const int lk = (p - r) & 15;
        gA[q] = A + (size_t)(m0 + r) * 4096 + lk * 8;
    }
    // B packed frags: kc = kt*4 + wk, cb = ci*4 + j; 16B/lane coalesced.
    const __bf16* gB[4];
#pragma unroll
    for (int j = 0; j < 4; ++j)
        gB[j] = Bp + ((size_t)((wk * 32 + (ci * 4 + j)) * 64 + lane)) * 8;

    // A frag offsets (elements): row = i*16+lr, k-chunk wk*4+quad.
    const int posw = ((wk * 4 + quad + lr) & 15) * 8;
    int foffA[4];
#pragma unroll
    for (int i = 0; i < 4; ++i) foffA[i] = (i * 16 + lr) * 128 + posw;

    f32x4 acc[4][4] = {};
    bf16x8 bv0[4], bv1[4], bv2[4], bv3[4];

    // prologue: stage tiles 0,1,2 into bufs 0,1,2 (batch order = vmcnt order)
#pragma unroll
    for (int q = 0; q < 4; ++q) async_copy16(gA[q], smem + q * 4096 + tx * 16);
#pragma unroll
    for (int j = 0; j < 4; ++j) bv0[j] = *(const bf16x8*)(gB[j]);
    asm volatile("" ::: "memory");
#pragma unroll
    for (int q = 0; q < 4; ++q) async_copy16(gA[q] + 128, smem + 16384 + q * 4096 + tx * 16);
#pragma unroll
    for (int j = 0; j < 4; ++j) bv1[j] = *(const bf16x8*)(gB[j] + 65536);
    asm volatile("" ::: "memory");
#pragma unroll
    for (int q = 0; q < 4; ++q) async_copy16(gA[q] + 256, smem + 32768 + q * 4096 + tx * 16);
#pragma unroll
    for (int j = 0; j < 4; ++j) bv2[j] = *(const bf16x8*)(gB[j] + 131072);
    asm volatile("" ::: "memory");

#define GCN_STEP(KT, P, WAIT, PF, CUR, NXT)                                    \
    {                                                                          \
        asm volatile(WAIT ::: "memory");                                       \
        __builtin_amdgcn_s_barrier();                                          \
        const __bf16* Ab = (const __bf16*)(smem + (P) * 16384);                \
        bf16x8 af[4];                                                          \
        _Pragma("unroll") for (int i = 0; i < 4; ++i)                          \
            af[i] = *(const bf16x8*)(Ab + foffA[i]);                           \
        if (PF) {                                                              \
            const int nt_ = (KT) + 3;                                          \
            unsigned char* bo_ = smem + (((P) + 3) & 3) * 16384;               \
            _Pragma("unroll") for (int q = 0; q < 4; ++q)                      \
                async_copy16(gA[q] + nt_ * 128, bo_ + q * 4096 + tx * 16);     \
            _Pragma("unroll") for (int j = 0; j < 4; ++j)                      \
                NXT[j] = *(const bf16x8*)(gB[j] + (size_t)nt_ * 65536);        \
        }                                                                      \
        __builtin_amdgcn_s_setprio(1);                                         \
        _Pragma("unroll") for (int i = 0; i < 4; ++i)                          \
            _Pragma("unroll") for (int j = 0; j < 4; ++j)                      \
                acc[i][j] = __builtin_amdgcn_mfma_f32_16x16x32_bf16(           \
                    af[i], CUR[j], acc[i][j], 0, 0, 0);                        \
        __builtin_amdgcn_s_setprio(0);                                         \
    }

    for (int kt = 0; kt < 28; kt += 4) {
        GCN_STEP(kt + 0, 0, "s_waitcnt vmcnt(16) lgkmcnt(0)", 1, bv0, bv3)
        GCN_STEP(kt + 1, 1, "s_waitcnt vmcnt(16) lgkmcnt(0)", 1, bv1, bv0)
        GCN_STEP(kt + 2, 2, "s_waitcnt vmcnt(16) lgkmcnt(0)", 1, bv2, bv1)
        GCN_STEP(kt + 3, 3, "s_waitcnt vmcnt(16) lgkmcnt(0)", 1, bv3, bv2)
    }
    GCN_STEP(28, 0, "s_waitcnt vmcnt(16) lgkmcnt(0)", 1, bv0, bv3)
    GCN_STEP(29, 1, "s_waitcnt vmcnt(16) lgkmcnt(0)", 0, bv1, bv0)
    GCN_STEP(30, 2, "s_waitcnt vmcnt(8) lgkmcnt(0)",  0, bv2, bv1)
    GCN_STEP(31, 3, "s_waitcnt vmcnt(0) lgkmcnt(0)",  0, bv3, bv2)
#undef GCN_STEP

    // ---- cross-wave k-reduce: linear t-major exchange (conflict-free) ----
    __syncthreads();
    float* part = (float*)smem;                        // 2 slots x 16KB
    const int sb = (wk >> 1) * 4096;
    if (wk & 1) {                                      // wk 1,3 write
#pragma unroll
        for (int t = 0; t < 16; ++t)
            *(f32x4*)(part + sb + t * 256 + lane * 4) = acc[t >> 2][t & 3];
    }
    __syncthreads();
    if (!(wk & 1)) {                                   // wk 0,2 add partner
#pragma unroll
        for (int t = 0; t < 16; ++t)
            acc[t >> 2][t & 3] += *(const f32x4*)(part + sb + t * 256 + lane * 4);
    }
    __syncthreads();
    if (wk == 2) {                                     // wk 2 writes its sum
#pragma unroll
        for (int t = 0; t < 16; ++t)
            *(f32x4*)(part + t * 256 + lane * 4) = acc[t >> 2][t & 3];
    }
    __syncthreads();
    float* Ct = (float*)(smem + 32768);                // [64][66]
    if (wk == 0) {                                     // full sum + transpose
#pragma unroll
        for (int t = 0; t < 16; ++t)
            acc[t >> 2][t & 3] += *(const f32x4*)(part + t * 256 + lane * 4);
        // C/D: col=lane&15, row=quad*4+reg (harness-verified)
#pragma unroll
        for (int i = 0; i < 4; ++i)
#pragma unroll
            for (int j = 0; j < 4; ++j)
#pragma unroll
                for (int r = 0; r < 4; ++r)
                    Ct[(i * 16 + quad * 4 + r) * 66 + j * 16 + lr] = acc[i][j][r];
    }
    __syncthreads();

    if (MODE == 0) {
#pragma unroll
        for (int it = 0; it < 2; ++it) {
            const int g = it * 256 + tx;           // 512 packed chunks/block
            const int lp = g & 63, cbl = (g >> 6) & 3, kcl = g >> 8;
            const int cl = cbl * 16 + (lp & 15);
            const float bf = ba[cl & 3];
            const int mb = kcl * 32 + ((lp >> 4) & 3) * 8;
            bf16x8 o;
#pragma unroll
            for (int j = 0; j < 8; ++j)
                o[j] = (__bf16)fmaxf(Ct[(mb + j) * 66 + cl] + bf, 0.f);
            *(bf16x8*)(Op + ((size_t)((mi * 2 + kcl) * 32 + (ci * 4 + cbl)) * 64 + lp) * 8) = o;
        }
    } else if (MODE == 1) {
        float W2l[16], W3l[12], bl2[4];
#pragma unroll
        for (int i = 0; i < 16; ++i) W2l[i] = Wa[i];
#pragma unroll
        for (int i = 0; i < 12; ++i) W3l[i] = Wb[i];
#pragma unroll
        for (int i = 0; i < 4; ++i) bl2[i] = ba[i];
#pragma unroll
        for (int it = 0; it < 2; ++it) {
            const int g = it * 256 + tx;
            const int lp = g & 63, cbl = (g >> 6) & 3, kcl = g >> 8;
            const int cl = cbl * 16 + (lp & 15);
            const int bloc = cl >> 2, f3 = cl & 3;
            const int mb = kcl * 32 + ((lp >> 4) & 3) * 8;
            bf16x8 o;
#pragma unroll
            for (int j = 0; j < 8; ++j) {
                const float* row = &Ct[(mb + j) * 66 + bloc * 4];
                float v = 0.f;
                if (f3 < 3) {
#pragma unroll
                    for (int fo = 0; fo < 4; ++fo) {
                        const float tmp = fmaxf(row[0] * W2l[fo] + row[1] * W2l[4 + fo] +
                                                row[2] * W2l[8 + fo] + row[3] * W2l[12 + fo] +
                                                bl2[fo], 0.f);
                        const float w3a = W3l[fo * 3 + 0], w3b = W3l[fo * 3 + 1],
                                    w3c = W3l[fo * 3 + 2];
                        v += tmp * (f3 == 0 ? w3a : (f3 == 1 ? w3b : w3c));
                    }
                }
                o[j] = (__bf16)v;                  // f3==3 -> 0 pad column
            }
            *(bf16x8*)(Op + ((size_t)((mi * 2 + kcl) * 32 + (ci * 4 + cbl)) * 64 + lp) * 8) = o;
        }
    } else {
        const int m_l = tx & 63, cq = tx >> 6;
#pragma unroll
        for (int t = 0; t < 16; ++t) {
            const int cl = cq * 16 + t;
            const int c = c0 + cl, b = c >> 2, f = c & 3;
            if (f < 3)
                H3out[(size_t)(b * 3 + f) * N_NODE + m0 + m_l] =
                    fmaxf(Ct[m_l * 66 + cl] + ba[f], 0.f);
        }
    }
}

// fc1 split-K partial sums: grid (64 n-chunks, 8 b-groups of 16).
__global__ __launch_bounds__(256) void fc1p_k(const float* __restrict__ H3,
                                              const float* __restrict__ Wfc,
                                              float* __restrict__ hid_acc) {
    __shared__ float hs[16 * 192];       // [b][f][n]
    __shared__ float red[4][16][64];
    const int tx = threadIdx.x;
    const int wv = tx >> 6, lane = tx & 63;
    const int n0 = blockIdx.x * 64;
    const int b0 = blockIdx.y * 16;

    for (int idx = tx; idx < 3072; idx += 256) {
        const int n = idx & 63, f = (idx >> 6) % 3, b = idx / 192;
        hs[idx] = H3[((size_t)((b0 + b) * 3 + f)) * N_NODE + n0 + n];
    }
    __syncthreads();

    float acc[16];
#pragma unroll
    for (int b = 0; b < 16; ++b) acc[b] = 0.f;
    if (lane < 54) {
        const int nb = wv * 16;
        for (int n = 0; n < 16; ++n) {
#pragma unroll
            for (int f = 0; f < 3; ++f) {
                const float w = Wfc[((size_t)(n0 + nb + n) * 3 + f) * 54 + lane];
#pragma unroll
                for (int b = 0; b < 16; ++b)
                    acc[b] += hs[b * 192 + f * 64 + nb + n] * w;
            }
        }
    }
#pragma unroll
    for (int b = 0; b < 16; ++b) red[wv][b][lane] = acc[b];
    __syncthreads();
    if (wv == 0 && lane < 54) {
        for (int b = 0; b < 16; ++b) {
            const float s = red[0][b][lane] + red[1][b][lane] +
                            red[2][b][lane] + red[3][b][lane];
            atomicAdd(&hid_acc[(b0 + b) * 54 + lane], s);
        }
    }
}

// out[b][a] = sum_j relu(hid_acc[b][j]+bfc[j]) * Wout[j][a] + bout[a]
__global__ __launch_bounds__(256) void fc2_k(const float* __restrict__ hid_acc,
                                             const float* __restrict__ bfc,
                                             const float* __restrict__ Wout,
                                             const float* __restrict__ bout,
                                             float* __restrict__ out) {
    const int tx = threadIdx.x;
    const int a  = blockIdx.x * 256 + tx;
    const int b0 = blockIdx.y * 4;
    __shared__ float hs[4 * 54];
    if (tx < 216) {
        const int j = tx % 54;
        hs[tx] = fmaxf(hid_acc[b0 * 54 + tx] + bfc[j], 0.f);
    }
    __syncthreads();
    float a0 = 0.f, a1 = 0.f, a2 = 0.f, a3 = 0.f;
    for (int j = 0; j < 54; ++j) {
        float w = Wout[(size_t)j * N_NODE + a];
        a0 += hs[0 * 54 + j] * w;
        a1 += hs[1 * 54 + j] * w;
        a2 += hs[2 * 54 + j] * w;
        a3 += hs[3 * 54 + j] * w;
    }
    float bo = bout[a];
    out[(size_t)(b0 + 0) * N_NODE + a] = a0 + bo;
    out[(size_t)(b0 + 1) * N_NODE + a] = a1 + bo;
    out[(size_t)(b0 + 2) * N_NODE + a] = a2 + bo;
    out[(size_t)(b0 + 3) * N_NODE + a] = a3 + bo;
}

extern "C" void kernel_launch(void* const* d_in, const int* in_sizes, int n_in,
                              void* d_out, int out_size, void* d_ws, size_t ws_size,
                              hipStream_t stream) {
    const float* X    = (const float*)d_in[0];
    const float* adj  = (const float*)d_in[1];
    const float* W1   = (const float*)d_in[2];
    const float* b1   = (const float*)d_in[3];
    const float* W2   = (const float*)d_in[4];
    const float* b2   = (const float*)d_in[5];
    const float* W3   = (const float*)d_in[6];
    const float* b3   = (const float*)d_in[7];
    const float* Wfc  = (const float*)d_in[8];
    const float* bfc  = (const float*)d_in[9];
    const float* Wout = (const float*)d_in[10];
    const float* bout = (const float*)d_in[11];
    float* out = (float*)d_out;

    // ws: adjB 32MB | G0 packed 4MB | H1 packed 4MB | H2g packed 4MB
    //   | H3 fp32 [384][4096] 6MB | hid [128][54]
    char* w = (char*)d_ws;
    __bf16* adjB = (__bf16*)w;
    __bf16* G0   = (__bf16*)(w + 33554432);
    __bf16* H1   = (__bf16*)(w + 33554432 + 4194304);
    __bf16* H2g  = (__bf16*)(w + 33554432 + 2 * 4194304);
    float*  H3   = (float*)(w + 33554432 + 3 * 4194304);
    float*  hid  = (float*)(w + 33554432 + 3 * 4194304 + 6291456);

    prep_k<<<9243, 256, 0, stream>>>(adj, adjB, X, W1, G0, hid);

    // stage 1: H1 = relu(adj @ G0 + b1)            (W1 pre-applied in prep)
    gcn_k<0><<<512, 256, 0, stream>>>(adjB, G0, nullptr, b1, nullptr, H1, nullptr);
    // stage 2: H2g = (relu(adj @ H1 @ W2 + b2)) @ W3, padded f=4
    gcn_k<1><<<512, 256, 0, stream>>>(adjB, H1, W2, b2, W3, H2g, nullptr);
    // stage 3: H3 = relu(adj @ H2g + b3), f<3, fp32
    gcn_k<2><<<512, 256, 0, stream>>>(adjB, H2g, nullptr, b3, nullptr, nullptr, H3);

    // FC head
    fc1p_k<<<dim3(64, 8), 256, 0, stream>>>(H3, Wfc, hid);
    fc2_k<<<dim3(16, 32), 256, 0, stream>>>(hid, bfc, Wout, bout, out);
}